// Round 1
// baseline (443.110 us; speedup 1.0000x reference)
//
#include <hip/hip_runtime.h>
#include <math.h>

typedef __bf16 bf16_t;
typedef __bf16 bf16x8 __attribute__((ext_vector_type(8)));
typedef float f32x4 __attribute__((ext_vector_type(4)));

#define N_TOK 4096
#define DMODEL 1024
#define FFN 1024
#define NEXP 8

#define BM 128
#define BN 128
#define BK 32
#define LDK 40   // padded LDS k-stride (bf16 elems): 32 + 8 keeps 16B alignment, breaks pow2 stride

// ---------------- prep: fp32 -> bf16 convert ----------------
__global__ void cvt_f32_to_bf16_kernel(const float* __restrict__ in, bf16_t* __restrict__ out, int n) {
  int i = (blockIdx.x * blockDim.x + threadIdx.x) * 8;
  if (i >= n) return;
  float4 a = *reinterpret_cast<const float4*>(in + i);
  float4 b = *reinterpret_cast<const float4*>(in + i + 4);
  bf16x8 o;
  o[0] = (bf16_t)a.x; o[1] = (bf16_t)a.y; o[2] = (bf16_t)a.z; o[3] = (bf16_t)a.w;
  o[4] = (bf16_t)b.x; o[5] = (bf16_t)b.y; o[6] = (bf16_t)b.z; o[7] = (bf16_t)b.w;
  *reinterpret_cast<bf16x8*>(out + i) = o;
}

// ---------------- prep: fp32 (R x C) -> bf16 transposed (C x R), batched ----------------
__global__ void transpose_to_bf16_kernel(const float* __restrict__ in, bf16_t* __restrict__ out,
                                         int R, int C) {
  __shared__ float tile[32][33];
  size_t base = (size_t)blockIdx.z * R * C;
  int c0 = blockIdx.x * 32, r0 = blockIdx.y * 32;
  int tx = threadIdx.x, ty = threadIdx.y;
#pragma unroll
  for (int i = 0; i < 32; i += 8)
    tile[ty + i][tx] = in[base + (size_t)(r0 + ty + i) * C + (c0 + tx)];
  __syncthreads();
#pragma unroll
  for (int i = 0; i < 32; i += 8)
    out[base + (size_t)(c0 + ty + i) * R + (r0 + tx)] = (bf16_t)tile[tx][ty + i];
}

// ---------------- router: logits, softmax, top-2, shared sigmoid gate ----------------
__global__ void router_kernel(const float* __restrict__ x, const float* __restrict__ rw,
                              const float* __restrict__ gw, int* __restrict__ topi,
                              float* __restrict__ topw, float* __restrict__ sig,
                              int* __restrict__ counts) {
  const int t = blockIdx.x;
  const int lane = threadIdx.x;  // 64
  const float* xr = x + (size_t)t * DMODEL;
  float acc[NEXP] = {0.f, 0.f, 0.f, 0.f, 0.f, 0.f, 0.f, 0.f};
  float accg = 0.f;
#pragma unroll 4
  for (int i = 0; i < DMODEL / 64; i++) {
    int d = i * 64 + lane;
    float xv = xr[d];
    const float4* r = reinterpret_cast<const float4*>(rw + (size_t)d * NEXP);
    float4 r0 = r[0], r1 = r[1];
    acc[0] += xv * r0.x; acc[1] += xv * r0.y; acc[2] += xv * r0.z; acc[3] += xv * r0.w;
    acc[4] += xv * r1.x; acc[5] += xv * r1.y; acc[6] += xv * r1.z; acc[7] += xv * r1.w;
    accg += xv * gw[d];
  }
#pragma unroll
  for (int e = 0; e < NEXP; e++)
    for (int s = 32; s > 0; s >>= 1) acc[e] += __shfl_down(acc[e], s, 64);
  for (int s = 32; s > 0; s >>= 1) accg += __shfl_down(accg, s, 64);
  if (lane == 0) {
    float mx = acc[0];
#pragma unroll
    for (int e = 1; e < NEXP; e++) mx = fmaxf(mx, acc[e]);
    float p[NEXP], sum = 0.f;
#pragma unroll
    for (int e = 0; e < NEXP; e++) { p[e] = __expf(acc[e] - mx); sum += p[e]; }
    // top-2 on logits (monotone with probs; avoids exp monotonicity concerns); ties -> lower index
    int i1 = 0;
#pragma unroll
    for (int e = 1; e < NEXP; e++) if (acc[e] > acc[i1]) i1 = e;
    int i2 = (i1 == 0) ? 1 : 0;
#pragma unroll
    for (int e = 0; e < NEXP; e++) if (e != i1 && acc[e] > acc[i2]) i2 = e;
    float inv = 1.f / sum;
    topi[2 * t] = i1;     topw[2 * t] = p[i1] * inv;
    topi[2 * t + 1] = i2; topw[2 * t + 1] = p[i2] * inv;
    sig[t] = 1.f / (1.f + __expf(-accg));
    atomicAdd(&counts[i1], 1);
    atomicAdd(&counts[i2], 1);
  }
}

__global__ void scan_kernel(const int* __restrict__ counts, int* __restrict__ offsets,
                            int* __restrict__ cursors) {
  int o = 0;
  for (int e = 0; e < NEXP; e++) { offsets[e] = o; o += counts[e]; cursors[e] = 0; }
}

__global__ void gather_kernel(const int* __restrict__ topi, const float* __restrict__ topw,
                              const int* __restrict__ offsets, int* __restrict__ cursors,
                              int* __restrict__ slot_tok, float* __restrict__ slot_w) {
  int t = blockIdx.x * blockDim.x + threadIdx.x;
  if (t >= N_TOK) return;
#pragma unroll
  for (int j = 0; j < 2; j++) {
    int e = topi[2 * t + j];
    int pos = atomicAdd(&cursors[e], 1);
    int s = offsets[e] + pos;
    slot_tok[s] = t;
    slot_w[s] = topw[2 * t + j];
  }
}

// ---------------- elementwise: S = silu(gate) * up ----------------
__global__ void silu_mul_kernel(const bf16_t* __restrict__ GU, bf16_t* __restrict__ S) {
  int i = blockIdx.x * blockDim.x + threadIdx.x;  // one per 8 elems
  int t = i >> 7;
  int f = (i & 127) << 3;
  const bf16_t* grp = GU + (size_t)t * (2 * FFN) + f;
  bf16x8 g = *reinterpret_cast<const bf16x8*>(grp);
  bf16x8 u = *reinterpret_cast<const bf16x8*>(grp + FFN);
  bf16x8 o;
#pragma unroll
  for (int j = 0; j < 8; j++) {
    float gv = (float)g[j], uv = (float)u[j];
    o[j] = (bf16_t)(gv / (1.f + __expf(-gv)) * uv);
  }
  *reinterpret_cast<bf16x8*>(S + (size_t)t * FFN + f) = o;
}

// ---------------- main MFMA GEMM, 128x128 tile, BK=32 ----------------
// MODE 0: C(bf16) = A @ B            (shared gate_up; Cout stride N)
// MODE 1: H(bf16) = silu(Xg @ W1e)   (A rows gathered via slot_tok; per-expert B)
// MODE 2: out(f32) += w * (H @ W2e)  (atomicAdd scatter to tokens)
// MODE 3: out(f32) = sig[m] * (S @ Wd)  (plain store; initializes d_out)
template <int MODE>
__global__ __launch_bounds__(256) void gemm_kernel(
    const bf16_t* __restrict__ A, const bf16_t* __restrict__ B, void* __restrict__ Cout,
    int N, int K, const int* __restrict__ offsets, const int* __restrict__ counts,
    const int* __restrict__ slot_tok, const float* __restrict__ slot_w,
    const float* __restrict__ sig) {
  __shared__ bf16_t lds_a[BM * LDK];
  __shared__ bf16_t lds_b[BN * LDK];

  const int e = blockIdx.z;
  int m0, mEnd;
  const bf16_t* Bp = B;
  if (MODE == 1 || MODE == 2) {
    const int off = offsets[e], cnt = counts[e];
    m0 = off + (int)blockIdx.y * BM;
    mEnd = off + cnt;
    if (m0 >= mEnd) return;
    Bp += (size_t)e * N * K;
  } else {
    m0 = blockIdx.y * BM;
    mEnd = N_TOK;
  }
  const int n0 = blockIdx.x * BN;

  const int tid = threadIdx.x;
  const int lane = tid & 63;
  const int wave = tid >> 6;
  const int wm = (wave >> 1) * 64;
  const int wn = (wave & 1) * 64;
  const int qd = lane >> 4;
  const int lm = lane & 15;

  // staging: 128 rows x 64B per tile; thread handles rows (tid>>2) and (tid>>2)+64, chunk tid&3
  const int arow = tid >> 2;
  const int cc = tid & 3;
  const bf16_t* pa[2];
  const bf16_t* pb[2];
#pragma unroll
  for (int h = 0; h < 2; h++) {
    int s = m0 + arow + h * 64;
    int g;
    if (MODE == 1) g = (s < mEnd) ? slot_tok[s] : 0;
    else if (MODE == 2) g = (s < mEnd) ? s : (mEnd - 1);
    else g = s;
    pa[h] = A + (size_t)g * K;
    pb[h] = Bp + (size_t)(n0 + arow + h * 64) * K;
  }

  f32x4 acc[4][4] = {};

  for (int k0 = 0; k0 < K; k0 += BK) {
    __syncthreads();
#pragma unroll
    for (int h = 0; h < 2; h++) {
      *reinterpret_cast<uint4*>(&lds_a[(arow + h * 64) * LDK + cc * 8]) =
          *reinterpret_cast<const uint4*>(pa[h] + k0 + cc * 8);
      *reinterpret_cast<uint4*>(&lds_b[(arow + h * 64) * LDK + cc * 8]) =
          *reinterpret_cast<const uint4*>(pb[h] + k0 + cc * 8);
    }
    __syncthreads();
    bf16x8 af[4], bfr[4];
#pragma unroll
    for (int i = 0; i < 4; i++)
      af[i] = *reinterpret_cast<const bf16x8*>(&lds_a[(wm + i * 16 + lm) * LDK + qd * 8]);
#pragma unroll
    for (int j = 0; j < 4; j++)
      bfr[j] = *reinterpret_cast<const bf16x8*>(&lds_b[(wn + j * 16 + lm) * LDK + qd * 8]);
#pragma unroll
    for (int i = 0; i < 4; i++)
#pragma unroll
      for (int j = 0; j < 4; j++)
        acc[i][j] = __builtin_amdgcn_mfma_f32_16x16x32_bf16(af[i], bfr[j], acc[i][j], 0, 0, 0);
  }

  // epilogue: C row = (lane>>4)*4 + reg, col = lane&15  [HW-verified layout]
#pragma unroll
  for (int i = 0; i < 4; i++) {
#pragma unroll
    for (int r = 0; r < 4; r++) {
      const int gm = m0 + wm + i * 16 + qd * 4 + r;
      if ((MODE == 1 || MODE == 2) && gm >= mEnd) continue;
#pragma unroll
      for (int j = 0; j < 4; j++) {
        const int col = n0 + wn + j * 16 + lm;
        float v = acc[i][j][r];
        if (MODE == 0) {
          ((bf16_t*)Cout)[(size_t)gm * N + col] = (bf16_t)v;
        } else if (MODE == 1) {
          ((bf16_t*)Cout)[(size_t)gm * FFN + col] = (bf16_t)(v / (1.f + __expf(-v)));
        } else if (MODE == 2) {
          const int t = slot_tok[gm];
          atomicAdd(&((float*)Cout)[(size_t)t * DMODEL + col], slot_w[gm] * v);
        } else {
          ((float*)Cout)[(size_t)gm * DMODEL + col] = sig[gm] * v;
        }
      }
    }
  }
}

extern "C" void kernel_launch(void* const* d_in, const int* in_sizes, int n_in, void* d_out,
                              int out_size, void* d_ws, size_t ws_size, hipStream_t stream) {
  const float* x = (const float*)d_in[0];
  const float* rw = (const float*)d_in[1];
  const float* w1 = (const float*)d_in[2];
  const float* w2 = (const float*)d_in[3];
  const float* sgu = (const float*)d_in[4];
  const float* sdw = (const float*)d_in[5];
  const float* gw = (const float*)d_in[6];
  float* out = (float*)d_out;

  char* ws = (char*)d_ws;
  size_t off = 0;
  auto alloc = [&](size_t bytes) -> void* {
    void* p = ws + off;
    off += (bytes + 255) & ~(size_t)255;
    return p;
  };
  bf16_t* xb = (bf16_t*)alloc((size_t)N_TOK * DMODEL * 2);
  bf16_t* w1t = (bf16_t*)alloc((size_t)NEXP * DMODEL * FFN * 2);
  bf16_t* w2t = (bf16_t*)alloc((size_t)NEXP * DMODEL * FFN * 2);
  bf16_t* sgut = (bf16_t*)alloc((size_t)2 * FFN * DMODEL * 2);
  bf16_t* sdt = (bf16_t*)alloc((size_t)DMODEL * FFN * 2);
  bf16_t* GU = (bf16_t*)alloc((size_t)N_TOK * 2 * FFN * 2);  // aliased by H (disjoint lifetime)
  bf16_t* S = (bf16_t*)alloc((size_t)N_TOK * FFN * 2);
  int* topi = (int*)alloc(N_TOK * 2 * 4);
  float* topw = (float*)alloc(N_TOK * 2 * 4);
  float* sig = (float*)alloc(N_TOK * 4);
  int* slot_tok = (int*)alloc(N_TOK * 2 * 4);
  float* slot_w = (float*)alloc(N_TOK * 2 * 4);
  int* counts = (int*)alloc(NEXP * 4);
  int* offsets = (int*)alloc(NEXP * 4);
  int* cursors = (int*)alloc(NEXP * 4);
  bf16_t* H = GU;  // GU dead after silu_mul; H written after

  hipMemsetAsync(counts, 0, NEXP * 4, stream);

  // prep: bf16 copies / transposes
  cvt_f32_to_bf16_kernel<<<N_TOK * DMODEL / 8 / 256, 256, 0, stream>>>(x, xb, N_TOK * DMODEL);
  transpose_to_bf16_kernel<<<dim3(FFN / 32, DMODEL / 32, NEXP), dim3(32, 8), 0, stream>>>(
      w1, w1t, DMODEL, FFN);
  transpose_to_bf16_kernel<<<dim3(DMODEL / 32, FFN / 32, NEXP), dim3(32, 8), 0, stream>>>(
      w2, w2t, FFN, DMODEL);
  transpose_to_bf16_kernel<<<dim3(2 * FFN / 32, DMODEL / 32, 1), dim3(32, 8), 0, stream>>>(
      sgu, sgut, DMODEL, 2 * FFN);
  transpose_to_bf16_kernel<<<dim3(DMODEL / 32, FFN / 32, 1), dim3(32, 8), 0, stream>>>(
      sdw, sdt, FFN, DMODEL);

  // routing
  router_kernel<<<N_TOK, 64, 0, stream>>>(x, rw, gw, topi, topw, sig, counts);
  scan_kernel<<<1, 1, 0, stream>>>(counts, offsets, cursors);
  gather_kernel<<<N_TOK / 256, 256, 0, stream>>>(topi, topw, offsets, cursors, slot_tok, slot_w);

  // shared expert path
  gemm_kernel<0><<<dim3(2 * FFN / BN, N_TOK / BM, 1), 256, 0, stream>>>(
      xb, sgut, GU, 2 * FFN, DMODEL, nullptr, nullptr, nullptr, nullptr, nullptr);
  silu_mul_kernel<<<N_TOK * FFN / 8 / 256, 256, 0, stream>>>(GU, S);
  gemm_kernel<3><<<dim3(DMODEL / BN, N_TOK / BM, 1), 256, 0, stream>>>(
      S, sdt, out, DMODEL, FFN, nullptr, nullptr, nullptr, nullptr, sig);

  // routed expert path (after out initialized by mode-3; H aliases dead GU)
  gemm_kernel<1><<<dim3(FFN / BN, N_TOK / BM, NEXP), 256, 0, stream>>>(
      xb, w1t, H, FFN, DMODEL, offsets, counts, slot_tok, nullptr, nullptr);
  gemm_kernel<2><<<dim3(DMODEL / BN, N_TOK / BM, NEXP), 256, 0, stream>>>(
      H, w2t, out, DMODEL, FFN, offsets, counts, slot_tok, slot_w, nullptr);
}

// Round 2
// 320.745 us; speedup vs baseline: 1.3815x; 1.3815x over previous
//
#include <hip/hip_runtime.h>
#include <math.h>

typedef __bf16 bf16_t;
typedef __bf16 bf16x8 __attribute__((ext_vector_type(8)));
typedef float f32x4 __attribute__((ext_vector_type(4)));

#define N_TOK 4096
#define DMODEL 1024
#define FFN 1024
#define NEXP 8
#define HIST_BLK 16  // 4096/256

#define BM 128
#define BN 128
#define BK 32
#define LDK 40   // padded LDS k-stride (bf16 elems): 32 + 8 keeps 16B alignment, breaks pow2 stride

// ---------------- prep: fp32 -> bf16 convert ----------------
__global__ void cvt_f32_to_bf16_kernel(const float* __restrict__ in, bf16_t* __restrict__ out, int n) {
  int i = (blockIdx.x * blockDim.x + threadIdx.x) * 8;
  if (i >= n) return;
  float4 a = *reinterpret_cast<const float4*>(in + i);
  float4 b = *reinterpret_cast<const float4*>(in + i + 4);
  bf16x8 o;
  o[0] = (bf16_t)a.x; o[1] = (bf16_t)a.y; o[2] = (bf16_t)a.z; o[3] = (bf16_t)a.w;
  o[4] = (bf16_t)b.x; o[5] = (bf16_t)b.y; o[6] = (bf16_t)b.z; o[7] = (bf16_t)b.w;
  *reinterpret_cast<bf16x8*>(out + i) = o;
}

// ---------------- prep: fp32 (R x C) -> bf16 transposed (C x R), batched ----------------
__global__ void transpose_to_bf16_kernel(const float* __restrict__ in, bf16_t* __restrict__ out,
                                         int R, int C) {
  __shared__ float tile[32][33];
  size_t base = (size_t)blockIdx.z * R * C;
  int c0 = blockIdx.x * 32, r0 = blockIdx.y * 32;
  int tx = threadIdx.x, ty = threadIdx.y;
#pragma unroll
  for (int i = 0; i < 32; i += 8)
    tile[ty + i][tx] = in[base + (size_t)(r0 + ty + i) * C + (c0 + tx)];
  __syncthreads();
#pragma unroll
  for (int i = 0; i < 32; i += 8)
    out[base + (size_t)(c0 + ty + i) * R + (r0 + tx)] = (bf16_t)tile[tx][ty + i];
}

// ---------------- router: logits, softmax, top-2, shared sigmoid gate (NO atomics) ----------------
__global__ void router_kernel(const float* __restrict__ x, const float* __restrict__ rw,
                              const float* __restrict__ gw, int* __restrict__ topi,
                              float* __restrict__ topw, float* __restrict__ sig) {
  const int t = blockIdx.x;
  const int lane = threadIdx.x;  // 64
  const float* xr = x + (size_t)t * DMODEL;
  float acc[NEXP] = {0.f, 0.f, 0.f, 0.f, 0.f, 0.f, 0.f, 0.f};
  float accg = 0.f;
#pragma unroll 4
  for (int i = 0; i < DMODEL / 64; i++) {
    int d = i * 64 + lane;
    float xv = xr[d];
    const float4* r = reinterpret_cast<const float4*>(rw + (size_t)d * NEXP);
    float4 r0 = r[0], r1 = r[1];
    acc[0] += xv * r0.x; acc[1] += xv * r0.y; acc[2] += xv * r0.z; acc[3] += xv * r0.w;
    acc[4] += xv * r1.x; acc[5] += xv * r1.y; acc[6] += xv * r1.z; acc[7] += xv * r1.w;
    accg += xv * gw[d];
  }
#pragma unroll
  for (int e = 0; e < NEXP; e++)
    for (int s = 32; s > 0; s >>= 1) acc[e] += __shfl_down(acc[e], s, 64);
  for (int s = 32; s > 0; s >>= 1) accg += __shfl_down(accg, s, 64);
  if (lane == 0) {
    float mx = acc[0];
#pragma unroll
    for (int e = 1; e < NEXP; e++) mx = fmaxf(mx, acc[e]);
    float p[NEXP], sum = 0.f;
#pragma unroll
    for (int e = 0; e < NEXP; e++) { p[e] = __expf(acc[e] - mx); sum += p[e]; }
    int i1 = 0;
#pragma unroll
    for (int e = 1; e < NEXP; e++) if (acc[e] > acc[i1]) i1 = e;
    int i2 = (i1 == 0) ? 1 : 0;
#pragma unroll
    for (int e = 0; e < NEXP; e++) if (e != i1 && acc[e] > acc[i2]) i2 = e;
    float inv = 1.f / sum;
    topi[2 * t] = i1;     topw[2 * t] = p[i1] * inv;
    topi[2 * t + 1] = i2; topw[2 * t + 1] = p[i2] * inv;
    sig[t] = 1.f / (1.f + __expf(-accg));
  }
}

// ---------------- per-block expert histogram (LDS only, no global atomics) ----------------
__global__ void hist_kernel(const int* __restrict__ topi, int* __restrict__ block_counts) {
  __shared__ int h[NEXP];
  const int tid = threadIdx.x;
  if (tid < NEXP) h[tid] = 0;
  __syncthreads();
  const int t = blockIdx.x * 256 + tid;
  atomicAdd(&h[topi[2 * t]], 1);
  atomicAdd(&h[topi[2 * t + 1]], 1);
  __syncthreads();
  if (tid < NEXP) block_counts[blockIdx.x * NEXP + tid] = h[tid];
}

// ---------------- tiny serial scan: offsets, counts, per-block bases ----------------
__global__ void scan_kernel(const int* __restrict__ block_counts, int* __restrict__ offsets,
                            int* __restrict__ counts, int* __restrict__ block_base) {
  int o = 0;
  for (int e = 0; e < NEXP; e++) {
    int tot = 0;
    for (int b = 0; b < HIST_BLK; b++) {
      block_base[b * NEXP + e] = o + tot;
      tot += block_counts[b * NEXP + e];
    }
    offsets[e] = o;
    counts[e] = tot;
    o += tot;
  }
}

// ---------------- gather: per-block LDS cursors seeded from block_base ----------------
__global__ void gather_kernel(const int* __restrict__ topi, const float* __restrict__ topw,
                              const int* __restrict__ block_base, int* __restrict__ slot_tok,
                              float* __restrict__ slot_w, int* __restrict__ slot_of) {
  __shared__ int cur[NEXP];
  const int tid = threadIdx.x;
  if (tid < NEXP) cur[tid] = block_base[blockIdx.x * NEXP + tid];
  __syncthreads();
  const int t = blockIdx.x * 256 + tid;
#pragma unroll
  for (int j = 0; j < 2; j++) {
    int e = topi[2 * t + j];
    int s = atomicAdd(&cur[e], 1);  // LDS atomic: block-local, cheap
    slot_tok[s] = t;
    slot_w[s] = topw[2 * t + j];
    slot_of[2 * t + j] = s;
  }
}

// ---------------- elementwise: S = silu(gate) * up ----------------
__global__ void silu_mul_kernel(const bf16_t* __restrict__ GU, bf16_t* __restrict__ S) {
  int i = blockIdx.x * blockDim.x + threadIdx.x;  // one per 8 elems
  int t = i >> 7;
  int f = (i & 127) << 3;
  const bf16_t* grp = GU + (size_t)t * (2 * FFN) + f;
  bf16x8 g = *reinterpret_cast<const bf16x8*>(grp);
  bf16x8 u = *reinterpret_cast<const bf16x8*>(grp + FFN);
  bf16x8 o;
#pragma unroll
  for (int j = 0; j < 8; j++) {
    float gv = (float)g[j], uv = (float)u[j];
    o[j] = (bf16_t)(gv / (1.f + __expf(-gv)) * uv);
  }
  *reinterpret_cast<bf16x8*>(S + (size_t)t * FFN + f) = o;
}

// ---------------- combine: out[t] += Y[slot0] + Y[slot1] (gather, no atomics) ----------------
__global__ void combine_kernel(const bf16_t* __restrict__ Y, const int* __restrict__ slot_of,
                               float* __restrict__ out) {
  int i = blockIdx.x * blockDim.x + threadIdx.x;  // one per 8 elems
  int t = i >> 7;
  int d = (i & 127) << 3;
  int s0 = slot_of[2 * t], s1 = slot_of[2 * t + 1];
  bf16x8 a = *reinterpret_cast<const bf16x8*>(Y + (size_t)s0 * DMODEL + d);
  bf16x8 b = *reinterpret_cast<const bf16x8*>(Y + (size_t)s1 * DMODEL + d);
  float* o = out + (size_t)t * DMODEL + d;
  float4 o0 = *reinterpret_cast<float4*>(o);
  float4 o1 = *reinterpret_cast<float4*>(o + 4);
  o0.x += (float)a[0] + (float)b[0]; o0.y += (float)a[1] + (float)b[1];
  o0.z += (float)a[2] + (float)b[2]; o0.w += (float)a[3] + (float)b[3];
  o1.x += (float)a[4] + (float)b[4]; o1.y += (float)a[5] + (float)b[5];
  o1.z += (float)a[6] + (float)b[6]; o1.w += (float)a[7] + (float)b[7];
  *reinterpret_cast<float4*>(o) = o0;
  *reinterpret_cast<float4*>(o + 4) = o1;
}

// ---------------- main MFMA GEMM, 128x128 tile, BK=32 ----------------
// MODE 0: C(bf16) = A @ B            (shared gate_up; Cout stride N)
// MODE 1: H(bf16) = silu(Xg @ W1e)   (A rows gathered via slot_tok; per-expert B)
// MODE 2: Y(bf16) = w * (H @ W2e)    (plain slot-major store)
// MODE 3: out(f32) = sig[m] * (S @ Wd)  (plain store; initializes d_out)
template <int MODE>
__global__ __launch_bounds__(256) void gemm_kernel(
    const bf16_t* __restrict__ A, const bf16_t* __restrict__ B, void* __restrict__ Cout,
    int N, int K, const int* __restrict__ offsets, const int* __restrict__ counts,
    const int* __restrict__ slot_tok, const float* __restrict__ slot_w,
    const float* __restrict__ sig) {
  __shared__ bf16_t lds_a[BM * LDK];
  __shared__ bf16_t lds_b[BN * LDK];

  const int e = blockIdx.z;
  int m0, mEnd;
  const bf16_t* Bp = B;
  if (MODE == 1 || MODE == 2) {
    const int off = offsets[e], cnt = counts[e];
    m0 = off + (int)blockIdx.y * BM;
    mEnd = off + cnt;
    if (m0 >= mEnd) return;
    Bp += (size_t)e * N * K;
  } else {
    m0 = blockIdx.y * BM;
    mEnd = N_TOK;
  }
  const int n0 = blockIdx.x * BN;

  const int tid = threadIdx.x;
  const int lane = tid & 63;
  const int wave = tid >> 6;
  const int wm = (wave >> 1) * 64;
  const int wn = (wave & 1) * 64;
  const int qd = lane >> 4;
  const int lm = lane & 15;

  // staging: 128 rows x 64B per tile; thread handles rows (tid>>2) and (tid>>2)+64, chunk tid&3
  const int arow = tid >> 2;
  const int cc = tid & 3;
  const bf16_t* pa[2];
  const bf16_t* pb[2];
#pragma unroll
  for (int h = 0; h < 2; h++) {
    int s = m0 + arow + h * 64;
    int g;
    if (MODE == 1) g = (s < mEnd) ? slot_tok[s] : 0;
    else if (MODE == 2) g = (s < mEnd) ? s : (mEnd - 1);
    else g = s;
    pa[h] = A + (size_t)g * K;
    pb[h] = Bp + (size_t)(n0 + arow + h * 64) * K;
  }

  f32x4 acc[4][4] = {};

  for (int k0 = 0; k0 < K; k0 += BK) {
    __syncthreads();
#pragma unroll
    for (int h = 0; h < 2; h++) {
      *reinterpret_cast<uint4*>(&lds_a[(arow + h * 64) * LDK + cc * 8]) =
          *reinterpret_cast<const uint4*>(pa[h] + k0 + cc * 8);
      *reinterpret_cast<uint4*>(&lds_b[(arow + h * 64) * LDK + cc * 8]) =
          *reinterpret_cast<const uint4*>(pb[h] + k0 + cc * 8);
    }
    __syncthreads();
    bf16x8 af[4], bfr[4];
#pragma unroll
    for (int i = 0; i < 4; i++)
      af[i] = *reinterpret_cast<const bf16x8*>(&lds_a[(wm + i * 16 + lm) * LDK + qd * 8]);
#pragma unroll
    for (int j = 0; j < 4; j++)
      bfr[j] = *reinterpret_cast<const bf16x8*>(&lds_b[(wn + j * 16 + lm) * LDK + qd * 8]);
#pragma unroll
    for (int i = 0; i < 4; i++)
#pragma unroll
      for (int j = 0; j < 4; j++)
        acc[i][j] = __builtin_amdgcn_mfma_f32_16x16x32_bf16(af[i], bfr[j], acc[i][j], 0, 0, 0);
  }

  // epilogue: C row = (lane>>4)*4 + reg, col = lane&15  [HW-verified layout]
#pragma unroll
  for (int i = 0; i < 4; i++) {
#pragma unroll
    for (int r = 0; r < 4; r++) {
      const int gm = m0 + wm + i * 16 + qd * 4 + r;
      if ((MODE == 1 || MODE == 2) && gm >= mEnd) continue;
      const float wgt = (MODE == 2) ? slot_w[gm] : 0.f;
#pragma unroll
      for (int j = 0; j < 4; j++) {
        const int col = n0 + wn + j * 16 + lm;
        float v = acc[i][j][r];
        if (MODE == 0) {
          ((bf16_t*)Cout)[(size_t)gm * N + col] = (bf16_t)v;
        } else if (MODE == 1) {
          ((bf16_t*)Cout)[(size_t)gm * FFN + col] = (bf16_t)(v / (1.f + __expf(-v)));
        } else if (MODE == 2) {
          ((bf16_t*)Cout)[(size_t)gm * DMODEL + col] = (bf16_t)(wgt * v);
        } else {
          ((float*)Cout)[(size_t)gm * DMODEL + col] = sig[gm] * v;
        }
      }
    }
  }
}

extern "C" void kernel_launch(void* const* d_in, const int* in_sizes, int n_in, void* d_out,
                              int out_size, void* d_ws, size_t ws_size, hipStream_t stream) {
  const float* x = (const float*)d_in[0];
  const float* rw = (const float*)d_in[1];
  const float* w1 = (const float*)d_in[2];
  const float* w2 = (const float*)d_in[3];
  const float* sgu = (const float*)d_in[4];
  const float* sdw = (const float*)d_in[5];
  const float* gw = (const float*)d_in[6];
  float* out = (float*)d_out;

  char* ws = (char*)d_ws;
  size_t off = 0;
  auto alloc = [&](size_t bytes) -> void* {
    void* p = ws + off;
    off += (bytes + 255) & ~(size_t)255;
    return p;
  };
  bf16_t* xb = (bf16_t*)alloc((size_t)N_TOK * DMODEL * 2);
  bf16_t* w1t = (bf16_t*)alloc((size_t)NEXP * DMODEL * FFN * 2);
  bf16_t* w2t = (bf16_t*)alloc((size_t)NEXP * DMODEL * FFN * 2);
  bf16_t* sgut = (bf16_t*)alloc((size_t)2 * FFN * DMODEL * 2);
  bf16_t* sdt = (bf16_t*)alloc((size_t)DMODEL * FFN * 2);
  bf16_t* GU = (bf16_t*)alloc((size_t)N_TOK * 2 * FFN * 2);  // aliased by H (disjoint lifetime)
  bf16_t* S = (bf16_t*)alloc((size_t)N_TOK * FFN * 2);
  bf16_t* Y = (bf16_t*)alloc((size_t)N_TOK * 2 * DMODEL * 2);  // slot-major routed outputs
  int* topi = (int*)alloc(N_TOK * 2 * 4);
  float* topw = (float*)alloc(N_TOK * 2 * 4);
  float* sig = (float*)alloc(N_TOK * 4);
  int* slot_tok = (int*)alloc(N_TOK * 2 * 4);
  float* slot_w = (float*)alloc(N_TOK * 2 * 4);
  int* slot_of = (int*)alloc(N_TOK * 2 * 4);
  int* block_counts = (int*)alloc(HIST_BLK * NEXP * 4);
  int* block_base = (int*)alloc(HIST_BLK * NEXP * 4);
  int* counts = (int*)alloc(NEXP * 4);
  int* offsets = (int*)alloc(NEXP * 4);
  bf16_t* H = GU;  // GU dead after silu_mul; H written after

  // prep: bf16 copies / transposes
  cvt_f32_to_bf16_kernel<<<N_TOK * DMODEL / 8 / 256, 256, 0, stream>>>(x, xb, N_TOK * DMODEL);
  transpose_to_bf16_kernel<<<dim3(FFN / 32, DMODEL / 32, NEXP), dim3(32, 8), 0, stream>>>(
      w1, w1t, DMODEL, FFN);
  transpose_to_bf16_kernel<<<dim3(DMODEL / 32, FFN / 32, NEXP), dim3(32, 8), 0, stream>>>(
      w2, w2t, FFN, DMODEL);
  transpose_to_bf16_kernel<<<dim3(2 * FFN / 32, DMODEL / 32, 1), dim3(32, 8), 0, stream>>>(
      sgu, sgut, DMODEL, 2 * FFN);
  transpose_to_bf16_kernel<<<dim3(DMODEL / 32, FFN / 32, 1), dim3(32, 8), 0, stream>>>(
      sdw, sdt, FFN, DMODEL);

  // routing (no contended atomics anywhere)
  router_kernel<<<N_TOK, 64, 0, stream>>>(x, rw, gw, topi, topw, sig);
  hist_kernel<<<HIST_BLK, 256, 0, stream>>>(topi, block_counts);
  scan_kernel<<<1, 1, 0, stream>>>(block_counts, offsets, counts, block_base);
  gather_kernel<<<HIST_BLK, 256, 0, stream>>>(topi, topw, block_base, slot_tok, slot_w, slot_of);

  // shared expert path
  gemm_kernel<0><<<dim3(2 * FFN / BN, N_TOK / BM, 1), 256, 0, stream>>>(
      xb, sgut, GU, 2 * FFN, DMODEL, nullptr, nullptr, nullptr, nullptr, nullptr);
  silu_mul_kernel<<<N_TOK * FFN / 8 / 256, 256, 0, stream>>>(GU, S);
  gemm_kernel<3><<<dim3(DMODEL / BN, N_TOK / BM, 1), 256, 0, stream>>>(
      S, sdt, out, DMODEL, FFN, nullptr, nullptr, nullptr, nullptr, sig);

  // routed expert path (H aliases dead GU; Y slot-major, combined by gather)
  gemm_kernel<1><<<dim3(FFN / BN, N_TOK / BM, NEXP), 256, 0, stream>>>(
      xb, w1t, H, FFN, DMODEL, offsets, counts, slot_tok, nullptr, nullptr);
  gemm_kernel<2><<<dim3(DMODEL / BN, N_TOK / BM, NEXP), 256, 0, stream>>>(
      H, w2t, Y, DMODEL, FFN, offsets, counts, slot_tok, slot_w, nullptr);
  combine_kernel<<<N_TOK * DMODEL / 8 / 256, 256, 0, stream>>>(Y, slot_of, out);
}